// Round 19
// baseline (291.626 us; speedup 1.0000x reference)
//
#include <hip/hip_runtime.h>
#include <math.h>
#include <stdint.h>

#define NN 2048
#define HH 64

typedef _Float16 half8 __attribute__((ext_vector_type(8)));
typedef _Float16 half2_t __attribute__((ext_vector_type(2)));
typedef float f32x4 __attribute__((ext_vector_type(4)));

#define SH (1.0f / 256.0f)
#define INV_SH 256.0f
#define BPAD 132  // f32 row stride: 2-way bank phases (free)

#if defined(__has_builtin)
#if __has_builtin(__builtin_amdgcn_cvt_pkrtz)
#define PKRTZ(a, b) ((half2_t)__builtin_amdgcn_cvt_pkrtz((a), (b)))
#endif
#endif
#ifndef PKRTZ
#define PKRTZ(a, b) ((half2_t){(_Float16)(a), (_Float16)(b)})
#endif

union H8u { half2_t h2[4]; uint32_t u[4]; half8 h8; };

// hl word = pack2(f16(sLo - f32(hh.lo)), f16(sHi - f32(hh.hi))) via fma_mix.
#define MIX_LO(D, HHW, S)                                                      \
  asm("v_fma_mixlo_f16 %0, %1, -1.0, %2 op_sel:[0,0,0] op_sel_hi:[1,0,0]"      \
      : "=v"(D) : "v"(HHW), "v"(S))
#define MIX_HI(D, HHW, S)                                                      \
  asm("v_fma_mixhi_f16 %0, %1, -1.0, %2 op_sel:[1,0,0] op_sel_hi:[1,0,0]"      \
      : "+v"(D) : "v"(HHW), "v"(S))

// ---------- layer 0: x0 = relu((adj @ nf) @ W0 + b0), nf is (N,4) ----------
__global__ __launch_bounds__(256) void gcn0_kernel(const float* __restrict__ adj,
                                                   const float* __restrict__ nf,
                                                   const float* __restrict__ W0,
                                                   const float* __restrict__ b0,
                                                   float* __restrict__ xout) {
  int w = threadIdx.x >> 6;
  int l = threadIdx.x & 63;
  int i = blockIdx.x * 4 + w;
  const float* arow = adj + (size_t)i * NN;
  float s0 = 0.f, s1 = 0.f, s2 = 0.f, s3 = 0.f;
  for (int k = l; k < NN; k += 64) {
    float a = arow[k];
    float4 v = *(const float4*)(nf + (size_t)k * 4);
    s0 = fmaf(a, v.x, s0);
    s1 = fmaf(a, v.y, s1);
    s2 = fmaf(a, v.z, s2);
    s3 = fmaf(a, v.w, s3);
  }
  #pragma unroll
  for (int m = 32; m >= 1; m >>= 1) {
    s0 += __shfl_xor(s0, m, 64);
    s1 += __shfl_xor(s1, m, 64);
    s2 += __shfl_xor(s2, m, 64);
    s3 += __shfl_xor(s3, m, 64);
  }
  double y = (double)b0[l];
  y += (double)s0 * (double)W0[0 * HH + l];
  y += (double)s1 * (double)W0[1 * HH + l];
  y += (double)s2 * (double)W0[2 * HH + l];
  y += (double)s3 * (double)W0[3 * HH + l];
  float r = (float)y;
  xout[(size_t)i * HH + l] = r > 0.f ? r : 0.f;
}

// ---------- layers 1,2: xout = relu((adj @ xin) @ W + b); layer2 fuses A/B ----------
#define KT 128
__global__ __launch_bounds__(512) void gcnL_kernel(const float* __restrict__ adj,
                                                   const float* __restrict__ xin,
                                                   const float* __restrict__ W,
                                                   const float* __restrict__ b,
                                                   float* __restrict__ xout,
                                                   const float* __restrict__ We1,
                                                   const float* __restrict__ be1,
                                                   float* __restrict__ Aout,
                                                   float* __restrict__ Bout) {
  __shared__ float xs[KT][HH];        // 32 KB [kk][l]
  __shared__ float adjs[4][KT];       // 2 KB  [row][kk]
  __shared__ float sredp[8][4][HH];   // 8 KB  [wave][row][l]
  __shared__ float sredt[4][HH];      // 1 KB
  __shared__ float xr2[4][HH];        // 1 KB
  int tid = threadIdx.x;
  int w = tid >> 6, l = tid & 63;
  int i0 = blockIdx.x * 4;
  float acc0 = 0.f, acc1 = 0.f, acc2 = 0.f, acc3 = 0.f;
  for (int k0 = 0; k0 < NN; k0 += KT) {
    __syncthreads();
    const float4* xsrc = (const float4*)(xin + (size_t)k0 * HH);
    float4* xdst = (float4*)&xs[0][0];
    for (int idx = tid; idx < KT * HH / 4; idx += 512) xdst[idx] = xsrc[idx];
    for (int idx = tid; idx < 4 * KT / 4; idx += 512) {
      int r = idx >> 5, c4 = idx & 31;
      *(float4*)&adjs[r][c4 * 4] =
          *(const float4*)(adj + (size_t)(i0 + r) * NN + k0 + c4 * 4);
    }
    __syncthreads();
    int kbase = w * 16;
    #pragma unroll
    for (int kq = 0; kq < 4; ++kq) {
      int kk = kbase + kq * 4;
      float4 a0 = *(const float4*)&adjs[0][kk];
      float4 a1 = *(const float4*)&adjs[1][kk];
      float4 a2 = *(const float4*)&adjs[2][kk];
      float4 a3 = *(const float4*)&adjs[3][kk];
      float xv0 = xs[kk + 0][l];
      float xv1 = xs[kk + 1][l];
      float xv2 = xs[kk + 2][l];
      float xv3 = xs[kk + 3][l];
      acc0 = fmaf(a0.w, xv3, fmaf(a0.z, xv2, fmaf(a0.y, xv1, fmaf(a0.x, xv0, acc0))));
      acc1 = fmaf(a1.w, xv3, fmaf(a1.z, xv2, fmaf(a1.y, xv1, fmaf(a1.x, xv0, acc1))));
      acc2 = fmaf(a2.w, xv3, fmaf(a2.z, xv2, fmaf(a2.y, xv1, fmaf(a2.x, xv0, acc2))));
      acc3 = fmaf(a3.w, xv3, fmaf(a3.z, xv2, fmaf(a3.y, xv1, fmaf(a3.x, xv0, acc3))));
    }
  }
  sredp[w][0][l] = acc0;
  sredp[w][1][l] = acc1;
  sredp[w][2][l] = acc2;
  sredp[w][3][l] = acc3;
  __syncthreads();
  if (w < 4) {
    float s = 0.f;
    #pragma unroll
    for (int sw = 0; sw < 8; ++sw) s += sredp[sw][w][l];
    sredt[w][l] = s;
  }
  __syncthreads();
  if (w < 4) {
    double y = (double)b[l];
    #pragma unroll 8
    for (int d = 0; d < HH; ++d) y += (double)sredt[w][d] * (double)W[d * HH + l];
    float r = (float)y;
    float rres = r > 0.f ? r : 0.f;
    xout[(size_t)(i0 + w) * HH + l] = rres;
    if (Aout != nullptr) xr2[w][l] = rres;
  }
  if (Aout != nullptr) {
    __syncthreads();
    {
      int idx = tid;
      int rr = idx >> 7, c = idx & 127;
      const float* xr = xr2[rr];
      float accA = be1[c], accB = 0.f;
      #pragma unroll 8
      for (int d = 0; d < HH; ++d) {
        float xv = xr[d];
        accA = fmaf(xv, We1[d * 128 + c], accA);
        accB = fmaf(xv, We1[(HH + d) * 128 + c], accB);
      }
      Aout[(size_t)(i0 + rr) * 128 + c] = accA * SH;
      Bout[(size_t)(i0 + rr) * 128 + c] = accB * SH;
    }
  }
}

// ---------- one-shot We2 split: Wh/Wl f16 [c2][k] row-major ----------
__global__ __launch_bounds__(256) void wsplit_kernel(const float* __restrict__ We2,
                                                     _Float16* __restrict__ Whg,
                                                     _Float16* __restrict__ Wlg) {
  int idx = blockIdx.x * 256 + threadIdx.x;   // 0..8191
  int k = idx >> 6, c2 = idx & 63;
  float wv = We2[idx];
  _Float16 hi = (_Float16)wv;
  float lo = wv - (float)hi;
  Whg[c2 * 128 + k] = hi;
  Wlg[c2 * 128 + k] = (_Float16)lo;
}

// ---------- pair MLP via MFMA (split-f16), 32i x 32j tile, 8 waves ----------
// v12: TWO i-STREAMS PER PASS (2 passes x 2 rows). W/B fragment LDS reads are
// shared by both streams -> inner ds_read count HALVES (192->96 per wave;
// LDS floor ~65->~35 us, the largest pipe component). MFMA/VALU totals
// unchanged. acc 64 regs + W 32 + temps -> ~190 VGPR = 2 waves/SIMD, which
// is what we measure anyway (occ 25%).
__global__ __launch_bounds__(512, 2) void pair_kernel(const float* __restrict__ A,
                                                      const float* __restrict__ B,
                                                      const _Float16* __restrict__ Whg,
                                                      const _Float16* __restrict__ Wlg,
                                                      const float* __restrict__ be2,
                                                      const float* __restrict__ We3,
                                                      const float* __restrict__ be3,
                                                      float* __restrict__ out) {
  int j0 = blockIdx.x * 32;
  int i0 = blockIdx.y * 32;
  if (i0 >= j0 + 31) return;         // no pair (i<j) in tile
  __shared__ __align__(16) _Float16 Wst8[2048 * 8];  // 32 KB, [Wh|Wl] swizzled
  __shared__ __align__(16) float Bs[32][BPAD];       // 16.9 KB
  __shared__ float be2s[64];
  __shared__ float We3s[64];
  int tid = threadIdx.x;
  int w = tid >> 6, l = tid & 63;   // 8 waves
  int r = l & 15, g = l >> 4;

  {
    half8* Wst = (half8*)Wst8;
    #pragma unroll
    for (int t = 0; t < 4; ++t) {
      int idx = tid + t * 512;       // 0..2047
      int arr = idx >> 10;           // 0 = Wh, 1 = Wl
      int c = idx & 1023;
      int row = c >> 4, ch = c & 15;
      const half8* src = arr ? (const half8*)Wlg : (const half8*)Whg;
      Wst[arr * 1024 + row * 16 + (ch ^ (row & 15))] = src[c];
    }
  }
  #pragma unroll
  for (int t = 0; t < 2; ++t) {
    int idx = tid + t * 512;         // 0..1023
    int rr = idx >> 5, c4 = idx & 31;
    *(float4*)&Bs[rr][c4 * 4] = *(const float4*)(B + (size_t)(j0 + rr) * 128 + c4 * 4);
  }
  if (tid < 64) { be2s[tid] = be2[tid]; We3s[tid] = We3[tid]; }
  __syncthreads();

  const half8* Wst = (const half8*)Wst8;
  float be3v = be3[0];
  float w3[4], sb[4];
  #pragma unroll
  for (int nt = 0; nt < 4; ++nt) {
    w3[nt] = We3s[nt * 16 + r];
    sb[nt] = SH * be2s[nt * 16 + r];
  }

  #pragma unroll 1
  for (int ip = 0; ip < 2; ++ip) {
    int irA = w * 4 + ip * 2;        // wave-uniform
    int iA = i0 + irA, iB = iA + 1;
    if (iA >= j0 + 31) continue;     // iB > iA, so both streams skip
    const float* ArowA = A + (size_t)iA * 128;
    const float* ArowB = A + (size_t)iB * 128;
    f32x4 accA[2][4], accB[2][4];
    #pragma unroll
    for (int js = 0; js < 2; ++js) {
      #pragma unroll
      for (int nt = 0; nt < 4; ++nt) {
        accA[js][nt][0] = sb[nt]; accA[js][nt][1] = sb[nt];
        accA[js][nt][2] = sb[nt]; accA[js][nt][3] = sb[nt];
        accB[js][nt][0] = sb[nt]; accB[js][nt][1] = sb[nt];
        accB[js][nt][2] = sb[nt]; accB[js][nt][3] = sb[nt];
      }
    }
    #pragma unroll
    for (int ks = 0; ks < 4; ++ks) {
      int kb = ks * 32 + 8 * g;
      half8 wh[4], wl[4];
      #pragma unroll
      for (int nt = 0; nt < 4; ++nt) {
        int a = (nt * 16 + r) * 16 + ((ks * 4 + g) ^ r);
        wh[nt] = Wst[a];
        wl[nt] = Wst[1024 + a];
      }
      float4 aA0 = *(const float4*)(ArowA + kb);    // L1/L2-resident, uniform row
      float4 aA1 = *(const float4*)(ArowA + kb + 4);
      float4 aB0 = *(const float4*)(ArowB + kb);
      float4 aB1 = *(const float4*)(ArowB + kb + 4);
      #pragma unroll
      for (int js = 0; js < 2; ++js) {
        float4 b0 = *(const float4*)&Bs[js * 16 + r][kb];
        float4 b1 = *(const float4*)&Bs[js * 16 + r][kb + 4];
        // stream A
        float sA0 = fmaxf(aA0.x + b0.x, 0.f);
        float sA1 = fmaxf(aA0.y + b0.y, 0.f);
        float sA2 = fmaxf(aA0.z + b0.z, 0.f);
        float sA3 = fmaxf(aA0.w + b0.w, 0.f);
        float sA4 = fmaxf(aA1.x + b1.x, 0.f);
        float sA5 = fmaxf(aA1.y + b1.y, 0.f);
        float sA6 = fmaxf(aA1.z + b1.z, 0.f);
        float sA7 = fmaxf(aA1.w + b1.w, 0.f);
        H8u hhA, hlA;
        hhA.h2[0] = PKRTZ(sA0, sA1);
        hhA.h2[1] = PKRTZ(sA2, sA3);
        hhA.h2[2] = PKRTZ(sA4, sA5);
        hhA.h2[3] = PKRTZ(sA6, sA7);
        MIX_LO(hlA.u[0], hhA.u[0], sA0); MIX_HI(hlA.u[0], hhA.u[0], sA1);
        MIX_LO(hlA.u[1], hhA.u[1], sA2); MIX_HI(hlA.u[1], hhA.u[1], sA3);
        MIX_LO(hlA.u[2], hhA.u[2], sA4); MIX_HI(hlA.u[2], hhA.u[2], sA5);
        MIX_LO(hlA.u[3], hhA.u[3], sA6); MIX_HI(hlA.u[3], hhA.u[3], sA7);
        // stream B
        float sB0 = fmaxf(aB0.x + b0.x, 0.f);
        float sB1 = fmaxf(aB0.y + b0.y, 0.f);
        float sB2 = fmaxf(aB0.z + b0.z, 0.f);
        float sB3 = fmaxf(aB0.w + b0.w, 0.f);
        float sB4 = fmaxf(aB1.x + b1.x, 0.f);
        float sB5 = fmaxf(aB1.y + b1.y, 0.f);
        float sB6 = fmaxf(aB1.z + b1.z, 0.f);
        float sB7 = fmaxf(aB1.w + b1.w, 0.f);
        H8u hhB, hlB;
        hhB.h2[0] = PKRTZ(sB0, sB1);
        hhB.h2[1] = PKRTZ(sB2, sB3);
        hhB.h2[2] = PKRTZ(sB4, sB5);
        hhB.h2[3] = PKRTZ(sB6, sB7);
        MIX_LO(hlB.u[0], hhB.u[0], sB0); MIX_HI(hlB.u[0], hhB.u[0], sB1);
        MIX_LO(hlB.u[1], hhB.u[1], sB2); MIX_HI(hlB.u[1], hhB.u[1], sB3);
        MIX_LO(hlB.u[2], hhB.u[2], sB4); MIX_HI(hlB.u[2], hhB.u[2], sB5);
        MIX_LO(hlB.u[3], hhB.u[3], sB6); MIX_HI(hlB.u[3], hhB.u[3], sB7);
        #pragma unroll
        for (int nt = 0; nt < 4; ++nt) {
          accA[js][nt] = __builtin_amdgcn_mfma_f32_16x16x32_f16(hhA.h8, wh[nt], accA[js][nt], 0, 0, 0);
          accA[js][nt] = __builtin_amdgcn_mfma_f32_16x16x32_f16(hhA.h8, wl[nt], accA[js][nt], 0, 0, 0);
          accA[js][nt] = __builtin_amdgcn_mfma_f32_16x16x32_f16(hlA.h8, wh[nt], accA[js][nt], 0, 0, 0);
          accB[js][nt] = __builtin_amdgcn_mfma_f32_16x16x32_f16(hhB.h8, wh[nt], accB[js][nt], 0, 0, 0);
          accB[js][nt] = __builtin_amdgcn_mfma_f32_16x16x32_f16(hhB.h8, wl[nt], accB[js][nt], 0, 0, 0);
          accB[js][nt] = __builtin_amdgcn_mfma_f32_16x16x32_f16(hlB.h8, wh[nt], accB[js][nt], 0, 0, 0);
        }
      }
    }
    // epilogues for both i-streams
#define EPILOG(ACC, IVAR)                                                     \
    _Pragma("unroll")                                                         \
    for (int js = 0; js < 2; ++js) {                                          \
      float p0 = 0.f, p1 = 0.f, p2 = 0.f, p3 = 0.f;                           \
      _Pragma("unroll")                                                       \
      for (int nt = 0; nt < 4; ++nt) {                                        \
        f32x4 v = ACC[js][nt];                                                \
        p0 += fmaxf(v[0], 0.f) * w3[nt];                                      \
        p1 += fmaxf(v[1], 0.f) * w3[nt];                                      \
        p2 += fmaxf(v[2], 0.f) * w3[nt];                                      \
        p3 += fmaxf(v[3], 0.f) * w3[nt];                                      \
      }                                                                       \
      _Pragma("unroll")                                                       \
      for (int m = 1; m <= 8; m <<= 1) {                                      \
        p0 += __shfl_xor(p0, m, 64);                                          \
        p1 += __shfl_xor(p1, m, 64);                                          \
        p2 += __shfl_xor(p2, m, 64);                                          \
        p3 += __shfl_xor(p3, m, 64);                                          \
      }                                                                       \
      if (r == 0) {                                                           \
        int jb2 = j0 + js * 16 + 4 * g;                                       \
        int i = IVAR;                                                         \
        int j; float logit;                                                   \
        j = jb2 + 0;                                                          \
        if (j > i) {                                                          \
          logit = p0 * INV_SH + be3v;                                         \
          out[i * (NN - 1) - (i * (i - 1)) / 2 + (j - i - 1)] =               \
              1.0f / (1.0f + expf(-logit));                                   \
        }                                                                     \
        j = jb2 + 1;                                                          \
        if (j > i) {                                                          \
          logit = p1 * INV_SH + be3v;                                         \
          out[i * (NN - 1) - (i * (i - 1)) / 2 + (j - i - 1)] =               \
              1.0f / (1.0f + expf(-logit));                                   \
        }                                                                     \
        j = jb2 + 2;                                                          \
        if (j > i) {                                                          \
          logit = p2 * INV_SH + be3v;                                         \
          out[i * (NN - 1) - (i * (i - 1)) / 2 + (j - i - 1)] =               \
              1.0f / (1.0f + expf(-logit));                                   \
        }                                                                     \
        j = jb2 + 3;                                                          \
        if (j > i) {                                                          \
          logit = p3 * INV_SH + be3v;                                         \
          out[i * (NN - 1) - (i * (i - 1)) / 2 + (j - i - 1)] =               \
              1.0f / (1.0f + expf(-logit));                                   \
        }                                                                     \
      }                                                                       \
    }
    EPILOG(accA, iA)
    EPILOG(accB, iB)
#undef EPILOG
  }
}

extern "C" void kernel_launch(void* const* d_in, const int* in_sizes, int n_in,
                              void* d_out, int out_size, void* d_ws, size_t ws_size,
                              hipStream_t stream) {
  (void)in_sizes; (void)n_in; (void)out_size; (void)ws_size;
  const float* nf  = (const float*)d_in[0];
  const float* adj = (const float*)d_in[1];
  const float* W0  = (const float*)d_in[2];
  const float* b0  = (const float*)d_in[3];
  const float* W1  = (const float*)d_in[4];
  const float* b1  = (const float*)d_in[5];
  const float* W2  = (const float*)d_in[6];
  const float* b2  = (const float*)d_in[7];
  const float* We1 = (const float*)d_in[8];
  const float* be1 = (const float*)d_in[9];
  const float* We2 = (const float*)d_in[10];
  const float* be2 = (const float*)d_in[11];
  const float* We3 = (const float*)d_in[12];
  const float* be3 = (const float*)d_in[13];
  float* out = (float*)d_out;

  // Workspace layout (max 3584 KB):
  //  [0,512K):    x0, later overwritten by x2 (x0 dead after layer 1)
  //  [512K,1024K): x1
  //  [1024K,1040K): Whg ; [1040K,1056K): Wlg
  //  [1536K,2560K): Ab ; [2560K,3584K): Bb
  char* ws = (char*)d_ws;
  float* x0 = (float*)(ws);
  float* x1 = (float*)(ws + (512 << 10));
  float* x2 = (float*)(ws);                        // reuse x0 slot
  _Float16* Whg = (_Float16*)(ws + (1024 << 10));  // 16 KB
  _Float16* Wlg = (_Float16*)(ws + (1040 << 10));  // 16 KB
  float* Ab = (float*)(ws + (1536 << 10));         // 1 MB (pre-scaled)
  float* Bb = (float*)(ws + (2560 << 10));         // 1 MB (pre-scaled)

  wsplit_kernel<<<32, 256, 0, stream>>>(We2, Whg, Wlg);
  gcn0_kernel<<<NN / 4, 256, 0, stream>>>(adj, nf, W0, b0, x0);
  gcnL_kernel<<<NN / 4, 512, 0, stream>>>(adj, x0, W1, b1, x1,
                                          nullptr, nullptr, nullptr, nullptr);
  gcnL_kernel<<<NN / 4, 512, 0, stream>>>(adj, x1, W2, b2, x2,
                                          We1, be1, Ab, Bb);
  pair_kernel<<<dim3(NN / 32, NN / 32), 512, 0, stream>>>(Ab, Bb, Whg, Wlg,
                                                          be2, We3, be3, out);
}

// Round 20
// 251.099 us; speedup vs baseline: 1.1614x; 1.1614x over previous
//
#include <hip/hip_runtime.h>
#include <math.h>
#include <stdint.h>

#define NN 2048
#define HH 64

typedef _Float16 half8 __attribute__((ext_vector_type(8)));
typedef _Float16 half2_t __attribute__((ext_vector_type(2)));
typedef float f32x4 __attribute__((ext_vector_type(4)));

#define SH (1.0f / 256.0f)
#define INV_SH 256.0f
#define BPAD 132  // f32 row stride: 2-way bank phases (free)

#if defined(__has_builtin)
#if __has_builtin(__builtin_amdgcn_cvt_pkrtz)
#define PKRTZ(a, b) ((half2_t)__builtin_amdgcn_cvt_pkrtz((a), (b)))
#endif
#endif
#ifndef PKRTZ
#define PKRTZ(a, b) ((half2_t){(_Float16)(a), (_Float16)(b)})
#endif

union H8u { half2_t h2[4]; uint32_t u[4]; half8 h8; };

// hl word = pack2(f16(sLo - f32(hh.lo)), f16(sHi - f32(hh.hi))) via fma_mix:
// one instruction per half, f32 math, RNE round into the f16 lane.
#define MIX_LO(D, HHW, S)                                                      \
  asm("v_fma_mixlo_f16 %0, %1, -1.0, %2 op_sel:[0,0,0] op_sel_hi:[1,0,0]"      \
      : "=v"(D) : "v"(HHW), "v"(S))
#define MIX_HI(D, HHW, S)                                                      \
  asm("v_fma_mixhi_f16 %0, %1, -1.0, %2 op_sel:[1,0,0] op_sel_hi:[1,0,0]"      \
      : "+v"(D) : "v"(HHW), "v"(S))

// ---------- layer 0: x0 = relu((adj @ nf) @ W0 + b0), nf is (N,4) ----------
__global__ __launch_bounds__(256) void gcn0_kernel(const float* __restrict__ adj,
                                                   const float* __restrict__ nf,
                                                   const float* __restrict__ W0,
                                                   const float* __restrict__ b0,
                                                   float* __restrict__ xout) {
  int w = threadIdx.x >> 6;
  int l = threadIdx.x & 63;
  int i = blockIdx.x * 4 + w;
  const float* arow = adj + (size_t)i * NN;
  float s0 = 0.f, s1 = 0.f, s2 = 0.f, s3 = 0.f;
  for (int k = l; k < NN; k += 64) {
    float a = arow[k];
    float4 v = *(const float4*)(nf + (size_t)k * 4);
    s0 = fmaf(a, v.x, s0);
    s1 = fmaf(a, v.y, s1);
    s2 = fmaf(a, v.z, s2);
    s3 = fmaf(a, v.w, s3);
  }
  #pragma unroll
  for (int m = 32; m >= 1; m >>= 1) {
    s0 += __shfl_xor(s0, m, 64);
    s1 += __shfl_xor(s1, m, 64);
    s2 += __shfl_xor(s2, m, 64);
    s3 += __shfl_xor(s3, m, 64);
  }
  double y = (double)b0[l];
  y += (double)s0 * (double)W0[0 * HH + l];
  y += (double)s1 * (double)W0[1 * HH + l];
  y += (double)s2 * (double)W0[2 * HH + l];
  y += (double)s3 * (double)W0[3 * HH + l];
  float r = (float)y;
  xout[(size_t)i * HH + l] = r > 0.f ? r : 0.f;
}

// ---------- layers 1,2: xout = relu((adj @ xin) @ W + b); layer2 fuses A/B ----------
#define KT 128
__global__ __launch_bounds__(512) void gcnL_kernel(const float* __restrict__ adj,
                                                   const float* __restrict__ xin,
                                                   const float* __restrict__ W,
                                                   const float* __restrict__ b,
                                                   float* __restrict__ xout,
                                                   const float* __restrict__ We1,
                                                   const float* __restrict__ be1,
                                                   float* __restrict__ Aout,
                                                   float* __restrict__ Bout) {
  __shared__ float xs[KT][HH];        // 32 KB [kk][l]
  __shared__ float adjs[4][KT];       // 2 KB  [row][kk]
  __shared__ float sredp[8][4][HH];   // 8 KB  [wave][row][l] K-slice partials
  __shared__ float sredt[4][HH];      // 1 KB  full row sums
  __shared__ float xr2[4][HH];        // 1 KB
  int tid = threadIdx.x;
  int w = tid >> 6, l = tid & 63;
  int i0 = blockIdx.x * 4;
  float acc0 = 0.f, acc1 = 0.f, acc2 = 0.f, acc3 = 0.f;  // rows 0..3, K-slice [16w,16w+16)
  for (int k0 = 0; k0 < NN; k0 += KT) {
    __syncthreads();
    const float4* xsrc = (const float4*)(xin + (size_t)k0 * HH);
    float4* xdst = (float4*)&xs[0][0];
    for (int idx = tid; idx < KT * HH / 4; idx += 512) xdst[idx] = xsrc[idx];
    for (int idx = tid; idx < 4 * KT / 4; idx += 512) {
      int r = idx >> 5, c4 = idx & 31;
      *(float4*)&adjs[r][c4 * 4] =
          *(const float4*)(adj + (size_t)(i0 + r) * NN + k0 + c4 * 4);
    }
    __syncthreads();
    int kbase = w * 16;
    #pragma unroll
    for (int kq = 0; kq < 4; ++kq) {
      int kk = kbase + kq * 4;
      float4 a0 = *(const float4*)&adjs[0][kk];  // wave-uniform broadcast
      float4 a1 = *(const float4*)&adjs[1][kk];
      float4 a2 = *(const float4*)&adjs[2][kk];
      float4 a3 = *(const float4*)&adjs[3][kk];
      float xv0 = xs[kk + 0][l];
      float xv1 = xs[kk + 1][l];
      float xv2 = xs[kk + 2][l];
      float xv3 = xs[kk + 3][l];
      acc0 = fmaf(a0.w, xv3, fmaf(a0.z, xv2, fmaf(a0.y, xv1, fmaf(a0.x, xv0, acc0))));
      acc1 = fmaf(a1.w, xv3, fmaf(a1.z, xv2, fmaf(a1.y, xv1, fmaf(a1.x, xv0, acc1))));
      acc2 = fmaf(a2.w, xv3, fmaf(a2.z, xv2, fmaf(a2.y, xv1, fmaf(a2.x, xv0, acc2))));
      acc3 = fmaf(a3.w, xv3, fmaf(a3.z, xv2, fmaf(a3.y, xv1, fmaf(a3.x, xv0, acc3))));
    }
  }
  sredp[w][0][l] = acc0;
  sredp[w][1][l] = acc1;
  sredp[w][2][l] = acc2;
  sredp[w][3][l] = acc3;
  __syncthreads();
  if (w < 4) {
    float s = 0.f;
    #pragma unroll
    for (int sw = 0; sw < 8; ++sw) s += sredp[sw][w][l];
    sredt[w][l] = s;
  }
  __syncthreads();
  if (w < 4) {
    double y = (double)b[l];
    #pragma unroll 8
    for (int d = 0; d < HH; ++d) y += (double)sredt[w][d] * (double)W[d * HH + l];
    float r = (float)y;
    float rres = r > 0.f ? r : 0.f;
    xout[(size_t)(i0 + w) * HH + l] = rres;
    if (Aout != nullptr) xr2[w][l] = rres;
  }
  if (Aout != nullptr) {
    __syncthreads();
    {
      int idx = tid;                   // 0..511 covers 4 rows x 128 cols
      int rr = idx >> 7, c = idx & 127;
      const float* xr = xr2[rr];
      float accA = be1[c], accB = 0.f;
      #pragma unroll 8
      for (int d = 0; d < HH; ++d) {
        float xv = xr[d];
        accA = fmaf(xv, We1[d * 128 + c], accA);
        accB = fmaf(xv, We1[(HH + d) * 128 + c], accB);
      }
      Aout[(size_t)(i0 + rr) * 128 + c] = accA * SH;
      Bout[(size_t)(i0 + rr) * 128 + c] = accB * SH;
    }
  }
}

// ---------- one-shot We2 split: Wh/Wl f16 [c2][k] row-major ----------
__global__ __launch_bounds__(256) void wsplit_kernel(const float* __restrict__ We2,
                                                     _Float16* __restrict__ Whg,
                                                     _Float16* __restrict__ Wlg) {
  int idx = blockIdx.x * 256 + threadIdx.x;   // 0..8191
  int k = idx >> 6, c2 = idx & 63;
  float wv = We2[idx];
  _Float16 hi = (_Float16)wv;
  float lo = wv - (float)hi;
  Whg[c2 * 128 + k] = hi;
  Wlg[c2 * 128 + k] = (_Float16)lo;
}

// ---------- pair MLP via MFMA (split-f16), 32i x 32j tile, 8 waves ----------
// v11 (best measured: pair 170 us, occ 25%, VALU 54 + MFMA 25): js=2 keeps
// acc at 32 regs (VGPR 64 -> 8 waves/CU+); 512-thread blocks amortize the
// 32 KB W-tile; hl via fma_mix. R19's 2-stream variant (halved ds_read)
// regressed via occupancy 25->13.8% — reverted.
__global__ __launch_bounds__(512, 4) void pair_kernel(const float* __restrict__ A,
                                                      const float* __restrict__ B,
                                                      const _Float16* __restrict__ Whg,
                                                      const _Float16* __restrict__ Wlg,
                                                      const float* __restrict__ be2,
                                                      const float* __restrict__ We3,
                                                      const float* __restrict__ be3,
                                                      float* __restrict__ out) {
  int j0 = blockIdx.x * 32;
  int i0 = blockIdx.y * 32;
  if (i0 >= j0 + 31) return;         // no pair (i<j) in tile
  __shared__ __align__(16) _Float16 Wst8[2048 * 8];  // 32 KB, [Wh|Wl] swizzled
  __shared__ __align__(16) float Bs[32][BPAD];       // 16.9 KB
  __shared__ float be2s[64];
  __shared__ float We3s[64];
  int tid = threadIdx.x;
  int w = tid >> 6, l = tid & 63;   // 8 waves
  int r = l & 15, g = l >> 4;

  {
    half8* Wst = (half8*)Wst8;
    #pragma unroll
    for (int t = 0; t < 4; ++t) {
      int idx = tid + t * 512;       // 0..2047
      int arr = idx >> 10;           // 0 = Wh, 1 = Wl
      int c = idx & 1023;
      int row = c >> 4, ch = c & 15;
      const half8* src = arr ? (const half8*)Wlg : (const half8*)Whg;
      Wst[arr * 1024 + row * 16 + (ch ^ (row & 15))] = src[c];
    }
  }
  #pragma unroll
  for (int t = 0; t < 2; ++t) {
    int idx = tid + t * 512;         // 0..1023
    int rr = idx >> 5, c4 = idx & 31;
    *(float4*)&Bs[rr][c4 * 4] = *(const float4*)(B + (size_t)(j0 + rr) * 128 + c4 * 4);
  }
  if (tid < 64) { be2s[tid] = be2[tid]; We3s[tid] = We3[tid]; }
  __syncthreads();

  const half8* Wst = (const half8*)Wst8;
  float be3v = be3[0];
  float w3[4], sb[4];
  #pragma unroll
  for (int nt = 0; nt < 4; ++nt) {
    w3[nt] = We3s[nt * 16 + r];
    sb[nt] = SH * be2s[nt * 16 + r];
  }

  #pragma unroll 1
  for (int p = 0; p < 4; ++p) {
    int ir = w * 4 + p;              // wave-uniform, 0..31
    int i = i0 + ir;
    if (i >= j0 + 31) continue;
    const float* Arow = A + (size_t)i * 128;
    f32x4 acc[2][4];
    #pragma unroll
    for (int js = 0; js < 2; ++js) {
      #pragma unroll
      for (int nt = 0; nt < 4; ++nt) {
        acc[js][nt][0] = sb[nt]; acc[js][nt][1] = sb[nt];
        acc[js][nt][2] = sb[nt]; acc[js][nt][3] = sb[nt];
      }
    }
    #pragma unroll
    for (int ks = 0; ks < 4; ++ks) {
      int kb = ks * 32 + 8 * g;
      half8 wh[4], wl[4];
      #pragma unroll
      for (int nt = 0; nt < 4; ++nt) {
        int a = (nt * 16 + r) * 16 + ((ks * 4 + g) ^ r);
        wh[nt] = Wst[a];
        wl[nt] = Wst[1024 + a];
      }
      float4 a0 = *(const float4*)(Arow + kb);      // L1/L2-resident, uniform row
      float4 a1 = *(const float4*)(Arow + kb + 4);
      #pragma unroll
      for (int js = 0; js < 2; ++js) {
        float4 b0 = *(const float4*)&Bs[js * 16 + r][kb];
        float4 b1 = *(const float4*)&Bs[js * 16 + r][kb + 4];
        float s0 = fmaxf(a0.x + b0.x, 0.f);
        float s1 = fmaxf(a0.y + b0.y, 0.f);
        float s2 = fmaxf(a0.z + b0.z, 0.f);
        float s3 = fmaxf(a0.w + b0.w, 0.f);
        float s4 = fmaxf(a1.x + b1.x, 0.f);
        float s5 = fmaxf(a1.y + b1.y, 0.f);
        float s6 = fmaxf(a1.z + b1.z, 0.f);
        float s7 = fmaxf(a1.w + b1.w, 0.f);
        H8u hh, hl;
        hh.h2[0] = PKRTZ(s0, s1);
        hh.h2[1] = PKRTZ(s2, s3);
        hh.h2[2] = PKRTZ(s4, s5);
        hh.h2[3] = PKRTZ(s6, s7);
        MIX_LO(hl.u[0], hh.u[0], s0); MIX_HI(hl.u[0], hh.u[0], s1);
        MIX_LO(hl.u[1], hh.u[1], s2); MIX_HI(hl.u[1], hh.u[1], s3);
        MIX_LO(hl.u[2], hh.u[2], s4); MIX_HI(hl.u[2], hh.u[2], s5);
        MIX_LO(hl.u[3], hh.u[3], s6); MIX_HI(hl.u[3], hh.u[3], s7);
        #pragma unroll
        for (int nt = 0; nt < 4; ++nt) {
          acc[js][nt] = __builtin_amdgcn_mfma_f32_16x16x32_f16(hh.h8, wh[nt], acc[js][nt], 0, 0, 0);
          acc[js][nt] = __builtin_amdgcn_mfma_f32_16x16x32_f16(hh.h8, wl[nt], acc[js][nt], 0, 0, 0);
          acc[js][nt] = __builtin_amdgcn_mfma_f32_16x16x32_f16(hl.h8, wh[nt], acc[js][nt], 0, 0, 0);
        }
      }
    }
    // epilogue: h2 = relu(acc)/SH; logit = sum h2*We3 + be3; direct store
    #pragma unroll
    for (int js = 0; js < 2; ++js) {
      float p0 = 0.f, p1 = 0.f, p2 = 0.f, p3 = 0.f;
      #pragma unroll
      for (int nt = 0; nt < 4; ++nt) {
        f32x4 v = acc[js][nt];
        p0 += fmaxf(v[0], 0.f) * w3[nt];
        p1 += fmaxf(v[1], 0.f) * w3[nt];
        p2 += fmaxf(v[2], 0.f) * w3[nt];
        p3 += fmaxf(v[3], 0.f) * w3[nt];
      }
      #pragma unroll
      for (int m = 1; m <= 8; m <<= 1) {
        p0 += __shfl_xor(p0, m, 64);
        p1 += __shfl_xor(p1, m, 64);
        p2 += __shfl_xor(p2, m, 64);
        p3 += __shfl_xor(p3, m, 64);
      }
      if (r == 0) {
        int jb2 = j0 + js * 16 + 4 * g;
        int j;
        float logit;
        j = jb2 + 0;
        if (j > i) {
          logit = p0 * INV_SH + be3v;
          out[i * (NN - 1) - (i * (i - 1)) / 2 + (j - i - 1)] =
              1.0f / (1.0f + expf(-logit));
        }
        j = jb2 + 1;
        if (j > i) {
          logit = p1 * INV_SH + be3v;
          out[i * (NN - 1) - (i * (i - 1)) / 2 + (j - i - 1)] =
              1.0f / (1.0f + expf(-logit));
        }
        j = jb2 + 2;
        if (j > i) {
          logit = p2 * INV_SH + be3v;
          out[i * (NN - 1) - (i * (i - 1)) / 2 + (j - i - 1)] =
              1.0f / (1.0f + expf(-logit));
        }
        j = jb2 + 3;
        if (j > i) {
          logit = p3 * INV_SH + be3v;
          out[i * (NN - 1) - (i * (i - 1)) / 2 + (j - i - 1)] =
              1.0f / (1.0f + expf(-logit));
        }
      }
    }
  }
}

extern "C" void kernel_launch(void* const* d_in, const int* in_sizes, int n_in,
                              void* d_out, int out_size, void* d_ws, size_t ws_size,
                              hipStream_t stream) {
  (void)in_sizes; (void)n_in; (void)out_size; (void)ws_size;
  const float* nf  = (const float*)d_in[0];
  const float* adj = (const float*)d_in[1];
  const float* W0  = (const float*)d_in[2];
  const float* b0  = (const float*)d_in[3];
  const float* W1  = (const float*)d_in[4];
  const float* b1  = (const float*)d_in[5];
  const float* W2  = (const float*)d_in[6];
  const float* b2  = (const float*)d_in[7];
  const float* We1 = (const float*)d_in[8];
  const float* be1 = (const float*)d_in[9];
  const float* We2 = (const float*)d_in[10];
  const float* be2 = (const float*)d_in[11];
  const float* We3 = (const float*)d_in[12];
  const float* be3 = (const float*)d_in[13];
  float* out = (float*)d_out;

  // Workspace layout (max 3584 KB):
  //  [0,512K):    x0, later overwritten by x2 (x0 dead after layer 1)
  //  [512K,1024K): x1
  //  [1024K,1040K): Whg ; [1040K,1056K): Wlg
  //  [1536K,2560K): Ab ; [2560K,3584K): Bb
  char* ws = (char*)d_ws;
  float* x0 = (float*)(ws);
  float* x1 = (float*)(ws + (512 << 10));
  float* x2 = (float*)(ws);                        // reuse x0 slot
  _Float16* Whg = (_Float16*)(ws + (1024 << 10));  // 16 KB
  _Float16* Wlg = (_Float16*)(ws + (1040 << 10));  // 16 KB
  float* Ab = (float*)(ws + (1536 << 10));         // 1 MB (pre-scaled)
  float* Bb = (float*)(ws + (2560 << 10));         // 1 MB (pre-scaled)

  wsplit_kernel<<<32, 256, 0, stream>>>(We2, Whg, Wlg);
  gcn0_kernel<<<NN / 4, 256, 0, stream>>>(adj, nf, W0, b0, x0);
  gcnL_kernel<<<NN / 4, 512, 0, stream>>>(adj, x0, W1, b1, x1,
                                          nullptr, nullptr, nullptr, nullptr);
  gcnL_kernel<<<NN / 4, 512, 0, stream>>>(adj, x1, W2, b2, x2,
                                          We1, be1, Ab, Bb);
  pair_kernel<<<dim3(NN / 32, NN / 32), 512, 0, stream>>>(Ab, Bb, Whg, Wlg,
                                                          be2, We3, be3, out);
}